// Round 8
// baseline (33.198 us; speedup 1.0000x reference)
//
#include <hip/hip_runtime.h>
#include <hip/hip_bf16.h>

#define HOURS 24
#define NB 32
#define MM 128
#define EE 128

typedef short bf16x8 __attribute__((ext_vector_type(8)));
typedef float f32x4 __attribute__((ext_vector_type(4)));

__device__ __forceinline__ unsigned short f2bfu(float f) {
    __hip_bfloat16 h = __float2bfloat16(f);
    return __builtin_bit_cast(unsigned short, h);
}
__device__ __forceinline__ unsigned int pack2(float a, float b) {
    return (unsigned int)f2bfu(a) | ((unsigned int)f2bfu(b) << 16);
}
// swizzled short-index of 16B unit `unit` in row `row` of a [*][128] bf16 tile
__device__ __forceinline__ int swz8(int row, int unit) {
    return row * 128 + (((unit ^ (row & 7)) & 15) << 3);
}
// load 8 consecutive f32 from global, convert to bf16x8 fragment
__device__ __forceinline__ bf16x8 load_w_frag(const float* base) {
    float4 x = *(const float4*)base;
    float4 y = *(const float4*)(base + 4);
    union { unsigned int u[4]; bf16x8 v; } r;
    r.u[0] = pack2(x.x, x.y); r.u[1] = pack2(x.z, x.w);
    r.u[2] = pack2(y.x, y.y); r.u[3] = pack2(y.z, y.w);
    return r.v;
}

#define MFMA(a, b, c) __builtin_amdgcn_mfma_f32_16x16x32_bf16(a, b, c, 0, 0, 0)

// ---------------- Kernel 1: joint gather + Q/K/VT. 768 blocks (3 which x 8 eighths x 32 b)
__global__ __launch_bounds__(256, 3) void k_qkv(
    const int* __restrict__ time_seq, const int* __restrict__ full_seq,
    const int* __restrict__ user,
    const float* __restrict__ emb_t, const float* __restrict__ emb_u,
    const float* __restrict__ emb_loc,
    const float* __restrict__ Wq, const float* __restrict__ Wk, const float* __restrict__ Wv,
    short* __restrict__ qws, short* __restrict__ kws, short* __restrict__ vtws)
{
    __shared__ alignas(16) short Jl[16 * 128];   // 4KB
    int b = blockIdx.y;
    int bx = blockIdx.x;
    int which = bx >> 3;
    int m0 = (bx & 7) * 16;
    int tid = threadIdx.x;
    int l = tid & 63, w = tid >> 6;
    int lr = l & 15, lg = l >> 4;

    int uid = user[b];
    const float4* Eu4 = (const float4*)(emb_u + (size_t)uid * 128);
#pragma unroll
    for (int it = 0; it < 2; ++it) {
        int i4 = it * 256 + tid;          // 512 float4 (16 rows x 32)
        int mm = i4 >> 5, fq = i4 & 31;
        int m = m0 + mm;
        int t = time_seq[b * MM + m];
        int tim = (t - 1) % HOURS + 1;
        int loc = full_seq[b * MM + m];
        float4 a = ((const float4*)(emb_t + (size_t)tim * 128))[fq];
        float4 c = ((const float4*)(emb_loc + (size_t)loc * 128))[fq];
        float4 u = Eu4[fq];
        uint2 pk;
        pk.x = pack2(a.x + c.x + u.x, a.y + c.y + u.y);
        pk.y = pack2(a.z + c.z + u.z, a.w + c.w + u.w);
        *(uint2*)&Jl[swz8(mm, fq >> 1) + (fq & 1) * 4] = pk;
    }
    __syncthreads();

    if (which < 2) {
        const float* W = which ? Wk : Wq;
        short* outp = which ? kws : qws;
        bf16x8 af[2][4], bj[4];
#pragma unroll
        for (int nt = 0; nt < 2; ++nt) {
            int n = (2 * w + nt) * 16 + lr;
#pragma unroll
            for (int kf = 0; kf < 4; ++kf)
                af[nt][kf] = load_w_frag(W + (size_t)n * 128 + kf * 32 + lg * 8);
        }
#pragma unroll
        for (int kf = 0; kf < 4; ++kf)
            bj[kf] = *(const bf16x8*)&Jl[swz8(lr, kf * 4 + lg)];
        f32x4 acc[2];
        acc[0] = (f32x4){0.f, 0.f, 0.f, 0.f};
        acc[1] = (f32x4){0.f, 0.f, 0.f, 0.f};
#pragma unroll
        for (int nt = 0; nt < 2; ++nt)
#pragma unroll
            for (int kf = 0; kf < 4; ++kf)
                acc[nt] = MFMA(af[nt][kf], bj[kf], acc[nt]);
        int mg = m0 + lr;
#pragma unroll
        for (int nt = 0; nt < 2; ++nt) {
            int n0 = (2 * w + nt) * 16 + lg * 4;
            uint2 pk;
            pk.x = pack2(acc[nt][0], acc[nt][1]);
            pk.y = pack2(acc[nt][2], acc[nt][3]);
            *(uint2*)&outp[(size_t)(b * MM + mg) * EE + n0] = pk;
        }
    } else {
        bf16x8 bfr[2][4], aj[4];
#pragma unroll
        for (int nt = 0; nt < 2; ++nt) {
            int n = (2 * w + nt) * 16 + lr;
#pragma unroll
            for (int kf = 0; kf < 4; ++kf)
                bfr[nt][kf] = load_w_frag(Wv + (size_t)n * 128 + kf * 32 + lg * 8);
        }
#pragma unroll
        for (int kf = 0; kf < 4; ++kf)
            aj[kf] = *(const bf16x8*)&Jl[swz8(lr, kf * 4 + lg)];
        f32x4 acc[2];
        acc[0] = (f32x4){0.f, 0.f, 0.f, 0.f};
        acc[1] = (f32x4){0.f, 0.f, 0.f, 0.f};
#pragma unroll
        for (int nt = 0; nt < 2; ++nt)
#pragma unroll
            for (int kf = 0; kf < 4; ++kf)
                acc[nt] = MFMA(aj[kf], bfr[nt][kf], acc[nt]);
#pragma unroll
        for (int nt = 0; nt < 2; ++nt) {
            int ng = (2 * w + nt) * 16 + lr;
            int mp = m0 + lg * 4;
            uint2 pk;
            pk.x = pack2(acc[nt][0], acc[nt][1]);
            pk.y = pack2(acc[nt][2], acc[nt][3]);
            *(uint2*)&vtws[(size_t)(b * MM + ng) * MM + mp] = pk;
        }
    }
}

// ---------------- Kernel 2: attention, 8 q-rows per block, 512 blocks x 512 thr ----
__global__ __launch_bounds__(512, 4) void k_attn(
    const short* __restrict__ qws, const short* __restrict__ kws,
    const short* __restrict__ vtws,
    const float* __restrict__ mat1, const int* __restrict__ traj_len,
    const float* __restrict__ esl, const float* __restrict__ esu,
    const float* __restrict__ etl, const float* __restrict__ etu,
    short* __restrict__ saws)
{
    __shared__ alignas(16) float Sf[8 * 132];    // 4224B
    __shared__ alignas(16) short Pl[16 * 128];   // 4KB (rows 8-15 zeroed)
    __shared__ float coef[8];

    int b = blockIdx.y;
    int i0 = blockIdx.x * 8;
    int tid = threadIdx.x;
    int l = tid & 63, w = tid >> 6;        // 8 waves
    int lr = l & 15, lg = l >> 4;
    int tl = traj_len[b];
    int irow = i0 + w;                     // this wave's softmax row

    // mat1 preload: wave w = row irow, lane covers cols 2l, 2l+1
    float4 md = *(const float4*)&mat1[((size_t)(b * MM + irow) * MM + 2 * l) * 2];

    // zero P rows 8-15 (read by PV B-frags, cols discarded)
    if (tid < 512) ((unsigned int*)Pl)[512 + tid] = 0u;

    // coef: wave w computes coef[w]
    {
        const float* tb4[4] = {esl, esu, etl, etu};
        const float* t = tb4[w >> 1];
        int row = w & 1;
        float v = t[row * 128 + l] + t[row * 128 + 64 + l];
#pragma unroll
        for (int off = 32; off >= 1; off >>= 1) v += __shfl_xor(v, off, 64);
        if (l == 0) coef[w] = v;
    }

    // QK^T: wave w -> j-tile w
    {
        bf16x8 qf[4], bk[4];
#pragma unroll
        for (int kf = 0; kf < 4; ++kf) {
            qf[kf] = *(const bf16x8*)&qws[(size_t)(b * MM + i0 + (lr & 7)) * EE + kf * 32 + lg * 8];
            bk[kf] = *(const bf16x8*)&kws[(size_t)(b * MM + w * 16 + lr) * EE + kf * 32 + lg * 8];
        }
        f32x4 acc = (f32x4){0.f, 0.f, 0.f, 0.f};
#pragma unroll
        for (int kf = 0; kf < 4; ++kf) acc = MFMA(qf[kf], bk[kf], acc);
        if (lg < 2) {
#pragma unroll
            for (int r = 0; r < 4; ++r)
                Sf[(lg * 4 + r) * 132 + w * 16 + lr] = acc[r];
        }
    }
    __syncthreads();

    // softmax: wave w handles row irow; lane covers j = 2l, 2l+1
    {
        float2 sv = *(const float2*)&Sf[w * 132 + 2 * l];
        int mi = (irow < tl) ? 1 : 0;
        float c0_1 = coef[1] + coef[5];
        float c1_1 = (coef[3] - coef[1]) * 0.01f;
        float c2_1 = (coef[7] - coef[5]) * 0.01f;
        float c0_0 = coef[0] + coef[4];
        float c1_0 = (coef[2] - coef[0]) * 0.01f;
        float c2_0 = (coef[6] - coef[4]) * 0.01f;
        int mk0 = mi & ((2 * l) < tl ? 1 : 0);
        int mk1 = mi & ((2 * l + 1) < tl ? 1 : 0);
        float lg0 = sv.x + (mk0 ? c0_1 : c0_0) + (mk0 ? c1_1 : c1_0) * md.x + (mk0 ? c2_1 : c2_0) * md.y;
        float lg1 = sv.y + (mk1 ? c0_1 : c0_0) + (mk1 ? c1_1 : c1_0) * md.z + (mk1 ? c2_1 : c2_0) * md.w;
        float mx = fmaxf(lg0, lg1);
#pragma unroll
        for (int off = 32; off >= 1; off >>= 1) mx = fmaxf(mx, __shfl_xor(mx, off, 64));
        float e0 = __expf(lg0 - mx), e1 = __expf(lg1 - mx);
        float sum = e0 + e1;
#pragma unroll
        for (int off = 32; off >= 1; off >>= 1) sum += __shfl_xor(sum, off, 64);
        float inv = 1.0f / sum;
        *(unsigned int*)&Pl[swz8(w, l >> 2) + ((2 * l) & 7)] =
            pack2(e0 * inv * (float)mk0, e1 * inv * (float)mk1);
    }
    __syncthreads();

    // PV: sa^T = VT . P^T ; wave w -> e-tile w; store sa[i][e] for the 8 rows
    {
        bf16x8 af[4], bp[4];
#pragma unroll
        for (int kf = 0; kf < 4; ++kf) {
            bp[kf] = *(const bf16x8*)&Pl[swz8(lr, kf * 4 + lg)];
            af[kf] = *(const bf16x8*)&vtws[(size_t)(b * MM + w * 16 + lr) * MM + kf * 32 + lg * 8];
        }
        f32x4 acc = (f32x4){0.f, 0.f, 0.f, 0.f};
#pragma unroll
        for (int kf = 0; kf < 4; ++kf) acc = MFMA(af[kf], bp[kf], acc);
        if (lr < 8) {
            int ig = i0 + lr;
            int e0 = w * 16 + lg * 4;
            uint2 pk;
            pk.x = pack2(acc[0], acc[1]);
            pk.y = pack2(acc[2], acc[3]);
            *(uint2*)&saws[(size_t)(b * MM + ig) * EE + e0] = pk;
        }
    }
}

// ---------------- Kernel 3: final, 8 l's per block, 512 blocks x 512 thr ----------
__global__ __launch_bounds__(512, 4) void k_final(
    const short* __restrict__ saws, const int* __restrict__ posneg,
    const float* __restrict__ emb_loc, const float* __restrict__ mat2,
    const float* __restrict__ vecg, const int* __restrict__ traj_len,
    const float* __restrict__ esl, const float* __restrict__ esu,
    const float* __restrict__ etl, const float* __restrict__ etu,
    float* __restrict__ outp)
{
    __shared__ float coef[8], tms[128], bsv[128];
    __shared__ float PART[8][8];

    int b = blockIdx.y;
    int l0 = blockIdx.x * 8;
    int tid = threadIdx.x;
    int l = tid & 63, w = tid >> 6;        // 8 waves, wave w -> m-tile w
    int lr = l & 15, lg = l >> 4;
    int tl = traj_len[b];

    // cand A-frags (gather, rows l0 + (lr&7))
    int p = posneg[b * MM + l0 + (lr & 7)];
    bf16x8 caf[4];
#pragma unroll
    for (int kf = 0; kf < 4; ++kf)
        caf[kf] = load_w_frag(emb_loc + (size_t)p * 128 + kf * 32 + lg * 8);
    // mat2 preload for lg<2 (cols l0 + lg*4 .. +3 of row m = w*16+lr)
    float4 m2 = (float4){0.f, 0.f, 0.f, 0.f};
    if (lg < 2)
        m2 = *(const float4*)&mat2[(size_t)(b * MM + w * 16 + lr) * MM + l0 + lg * 4];
    // sa B-frags
    bf16x8 bsa[4];
#pragma unroll
    for (int kf = 0; kf < 4; ++kf)
        bsa[kf] = *(const bf16x8*)&saws[(size_t)(b * MM + w * 16 + lr) * EE + kf * 32 + lg * 8];

    // coef: wave w computes coef[w]
    {
        const float* tb4[4] = {esl, esu, etl, etu};
        const float* t = tb4[w >> 1];
        int row = w & 1;
        float v = t[row * 128 + l] + t[row * 128 + 64 + l];
#pragma unroll
        for (int off = 32; off >= 1; off >>= 1) v += __shfl_xor(v, off, 64);
        if (l == 0) coef[w] = v;
    }
    __syncthreads();
    if (tid < 128) {
        int vv = (tid < tl) ? 1 : 0;
        float ssl = vv ? coef[1] : coef[0];
        float ssu = vv ? coef[3] : coef[2];
        float stl = vv ? coef[5] : coef[4];
        float stu = vv ? coef[7] : coef[6];
        tms[tid] = ssl + stl + (stu - stl) * 0.01f * vecg[b * MM + tid];
        bsv[tid] = (ssu - ssl) * 0.01f;
    }
    __syncthreads();

    // G tile: D[l-offset][m] = cand . sa^T for m-tile w
    f32x4 acc = (f32x4){0.f, 0.f, 0.f, 0.f};
#pragma unroll
    for (int kf = 0; kf < 4; ++kf) acc = MFMA(caf[kf], bsa[kf], acc);
    int m = w * 16 + lr;
    float wt = tms[m], wb = bsv[m];
    float val[4];
    val[0] = acc[0] * (wt + wb * m2.x);
    val[1] = acc[1] * (wt + wb * m2.y);
    val[2] = acc[2] * (wt + wb * m2.z);
    val[3] = acc[3] * (wt + wb * m2.w);
#pragma unroll
    for (int r = 0; r < 4; ++r) {
        float v = val[r];
        v += __shfl_xor(v, 1, 64);
        v += __shfl_xor(v, 2, 64);
        v += __shfl_xor(v, 4, 64);
        v += __shfl_xor(v, 8, 64);
        if (lr == 0 && lg < 2) PART[w][lg * 4 + r] = v;
    }
    __syncthreads();
    if (tid < 8) {
        float s = 0.f;
#pragma unroll
        for (int w8 = 0; w8 < 8; ++w8) s += PART[w8][tid];
        outp[b * MM + l0 + tid] = s;
    }
}

extern "C" void kernel_launch(void* const* d_in, const int* in_sizes, int n_in,
                              void* d_out, int out_size, void* d_ws, size_t ws_size,
                              hipStream_t stream) {
    const int* full_seq = (const int*)d_in[0];
    const int* time_seq = (const int*)d_in[1];
    const int* user     = (const int*)d_in[2];
    const int* posneg   = (const int*)d_in[3];
    const int* traj_len = (const int*)d_in[4];
    const float* mat1   = (const float*)d_in[5];
    const float* mat2   = (const float*)d_in[6];
    const float* vec    = (const float*)d_in[7];
    const float* emb_t  = (const float*)d_in[8];
    const float* emb_u  = (const float*)d_in[9];
    const float* emb_loc= (const float*)d_in[10];
    const float* emb_sl = (const float*)d_in[11];
    const float* emb_su = (const float*)d_in[12];
    const float* emb_tl = (const float*)d_in[13];
    const float* emb_tu = (const float*)d_in[14];
    const float* Wq     = (const float*)d_in[15];
    const float* Wk     = (const float*)d_in[16];
    const float* Wv     = (const float*)d_in[17];

    short* qws  = (short*)d_ws;
    short* kws  = qws + (size_t)NB * MM * EE;
    short* vtws = kws + (size_t)NB * MM * EE;
    short* saws = vtws + (size_t)NB * MM * EE;

    k_qkv<<<dim3(24, 32), 256, 0, stream>>>(time_seq, full_seq, user,
                                            emb_t, emb_u, emb_loc,
                                            Wq, Wk, Wv, qws, kws, vtws);
    k_attn<<<dim3(16, 32), 512, 0, stream>>>(qws, kws, vtws, mat1, traj_len,
                                             emb_sl, emb_su, emb_tl, emb_tu, saws);
    k_final<<<dim3(16, 32), 512, 0, stream>>>(saws, posneg, emb_loc, mat2, vec,
                                              traj_len, emb_sl, emb_su, emb_tl, emb_tu,
                                              (float*)d_out);
}